// Round 11
// baseline (423.109 us; speedup 1.0000x reference)
//
#include <hip/hip_runtime.h>

#define NTHR 256
#define NBLK 1024              // B / NTHR
#define NCHUNK 1024            // 256-slot chunks (cnt entries) — layout unchanged

typedef unsigned long long u64;
typedef float v2 __attribute__((ext_vector_type(2)));

// ---------------------------------------------------------------------------
// index of the (n+1)-th set bit of m (n 0-based), 6-step binary search
__device__ __forceinline__ int nth_set_bit(u64 m, unsigned n) {
    int pos = 0;
#pragma unroll
    for (int st = 32; st; st >>= 1) {
        u64 low = (1ull << (pos + st)) - 1ull;
        if ((unsigned)__popcll(m & low) <= n) pos += st;
    }
    return pos;
}

// ---------------------------------------------------------------------------
// MLP + hysteresis. Packed-FP32 pairs over output neurons (j, j+1).
// Per-ELEMENT arithmetic byte-identical to the validated scalar version.
// ---------------------------------------------------------------------------
__device__ __forceinline__ void mlp_update(
    const float lin, const float x, const float isOn,
    const float* __restrict__ W1, const float* __restrict__ b1,
    const float* __restrict__ W2, const float* __restrict__ b2,
    const float* __restrict__ W3, const float* __restrict__ b3,
    float& x_new, float& isOn_new, bool& off)
{
    off = (isOn <= 0.5f);

    const v2* __restrict__ W1r0 = (const v2*)W1;          // row 0 (lin weights)
    const v2* __restrict__ W1r1 = (const v2*)(W1 + 32);   // row 1 (x weights)
    const v2* __restrict__ b1p  = (const v2*)b1;
    const v2* __restrict__ b2p  = (const v2*)b2;

    const v2 linv = { lin, lin };
    const v2 xv   = { x, x };
    const v2 zero = { 0.0f, 0.0f };

    v2 h1v[16];
#pragma unroll
    for (int jp = 0; jp < 16; ++jp) {
        v2 a = linv * W1r0[jp];                           // v_pk_mul_f32
        a = __builtin_elementwise_fma(xv, W1r1[jp], a);   // v_pk_fma_f32
        a = a + b1p[jp];                                  // v_pk_add_f32
        h1v[jp] = __builtin_elementwise_max(a, zero);     // v_pk_max_f32
    }

    float o = 0.0f;
#pragma unroll
    for (int jp = 0; jp < 16; ++jp) {
        v2 a = { 0.0f, 0.0f };
        const v2* __restrict__ w2col = (const v2*)(W2) + jp;  // stride 16 v2/row
#pragma unroll
        for (int kp = 0; kp < 16; ++kp) {
            a = __builtin_elementwise_fma(h1v[kp].xx, w2col[(2 * kp) * 16], a);
            a = __builtin_elementwise_fma(h1v[kp].yy, w2col[(2 * kp + 1) * 16], a);
        }
        a = a + b2p[jp];
        const float ax = fmaxf(a.x, 0.0f);
        const float ay = fmaxf(a.y, 0.0f);
        o = fmaf(ax, W3[2 * jp], o);
        o = fmaf(ay, W3[2 * jp + 1], o);
    }
    o += b3[0];

    const float plant = o * 10.0f;
    const float tm = x - plant;
    x_new = off ? tm : tm + 10.0f;
    isOn_new = off ? ((x_new <= 66.0f) ? 1.0f : isOn)
                   : ((x_new > 78.0f) ? 0.0f : isOn);
}

// ---------------------------------------------------------------------------
// One kernel per simulation step; 1024 blocks x 256 thr, 1 elem/thread.
// Consumer pull is fully wave-local: per-lane 16-chunk count load, shfl scan,
// 6-shfl lane search + 16-shfl count fetch + branchless 15-step walk.
// NO LDS / NO barriers on the pull path. Producer tail identical to the
// verified round-7 kernel. FP arithmetic untouched.
//   mode 0: first step  — x from input, isOn=0, no pull
//   mode 1: middle step — pull permuted state, write traj row t-1, compute
//   mode 2: final pull  — pull only, write last traj row
// ---------------------------------------------------------------------------
__global__ __launch_bounds__(NTHR, 4) void fused_kernel(
    const float2* __restrict__ inp,
    const float* __restrict__ W1, const float* __restrict__ b1,
    const float* __restrict__ W2, const float* __restrict__ b2,
    const float* __restrict__ W3, const float* __restrict__ b3,
    const float2* __restrict__ stPrev, const unsigned* __restrict__ cntPrev,
    const u64* __restrict__ mskPrev,
    float2* __restrict__ stNew, unsigned* __restrict__ cntNew,
    u64* __restrict__ mskNew,
    float* __restrict__ outRow,
    int mode)
{
    const int tid  = threadIdx.x;
    const int lane = tid & 63;
    const int wv   = tid >> 6;
    const int i    = blockIdx.x * NTHR + tid;

    float x, isOn;
    if (mode == 0) {
        const float2 iv = inp[i];
        x = iv.y; isOn = 0.0f;
    } else {
        // ---- wave-local scan: lane owns chunks [16*lane, 16*lane+16) ----
        const uint4* __restrict__ cp = (const uint4*)cntPrev;   // 256 uint4
        const uint4 c0 = cp[lane * 4 + 0];
        const uint4 c1 = cp[lane * 4 + 1];
        const uint4 c2 = cp[lane * 4 + 2];
        const uint4 c3 = cp[lane * 4 + 3];
        const unsigned gs = c0.x + c0.y + c0.z + c0.w
                          + c1.x + c1.y + c1.z + c1.w
                          + c2.x + c2.y + c2.z + c2.w
                          + c3.x + c3.y + c3.z + c3.w;
        unsigned incp = gs;
#pragma unroll
        for (int d = 1; d < 64; d <<= 1) {
            unsigned v = __shfl_up(incp, d);
            if (lane >= d) incp += v;
        }
        const unsigned pre = incp - gs;          // excl prefix of 4096-slot groups
        const unsigned T   = __shfl(incp, 63);   // total off count

        // ---- branchless off/on lane search (shfls wave-uniform) ----
        const bool isOff = ((unsigned)i < T);
        const unsigned r = isOff ? (unsigned)i : (unsigned)i - T;
        int L = 0;
#pragma unroll
        for (int st = 32; st; st >>= 1) {
            const int cand = L + st;             // <= 63 always
            const unsigned pv = __shfl(pre, cand);
            const unsigned v = isOff ? pv : 4096u * (unsigned)cand - pv;
            if (v <= r) L = cand;
        }
        const unsigned preL = __shfl(pre, L);
        const unsigned base = isOff ? preL : 4096u * (unsigned)L - preL;
        unsigned rem = r - base;

        // fetch winning lane's 16 counts via shfl, transform for on-side
        unsigned d0  = __shfl(c0.x, L), d1  = __shfl(c0.y, L);
        unsigned d2  = __shfl(c0.z, L), d3  = __shfl(c0.w, L);
        unsigned d4  = __shfl(c1.x, L), d5  = __shfl(c1.y, L);
        unsigned d6  = __shfl(c1.z, L), d7  = __shfl(c1.w, L);
        unsigned d8  = __shfl(c2.x, L), d9  = __shfl(c2.y, L);
        unsigned d10 = __shfl(c2.z, L), d11 = __shfl(c2.w, L);
        unsigned d12 = __shfl(c3.x, L), d13 = __shfl(c3.y, L);
        unsigned d14 = __shfl(c3.z, L);
        if (!isOff) {
            d0 = 256u - d0;  d1 = 256u - d1;  d2 = 256u - d2;  d3 = 256u - d3;
            d4 = 256u - d4;  d5 = 256u - d5;  d6 = 256u - d6;  d7 = 256u - d7;
            d8 = 256u - d8;  d9 = 256u - d9;  d10 = 256u - d10; d11 = 256u - d11;
            d12 = 256u - d12; d13 = 256u - d13; d14 = 256u - d14;
        }
        unsigned b = (unsigned)L * 16u;
#define WSTEP(dv) { const bool g = (rem >= (dv)); if (g) { rem -= (dv); ++b; } }
        WSTEP(d0)  WSTEP(d1)  WSTEP(d2)  WSTEP(d3)
        WSTEP(d4)  WSTEP(d5)  WSTEP(d6)  WSTEP(d7)
        WSTEP(d8)  WSTEP(d9)  WSTEP(d10) WSTEP(d11)
        WSTEP(d12) WSTEP(d13) WSTEP(d14)
#undef WSTEP

        // ---- wave-mask select within chunk b (identical math to verified) ----
        const u64 mr0 = mskPrev[4 * b],     mr1 = mskPrev[4 * b + 1];
        const u64 mr2 = mskPrev[4 * b + 2], mr3 = mskPrev[4 * b + 3];
        const u64 m0 = isOff ? mr0 : ~mr0;
        const u64 m1 = isOff ? mr1 : ~mr1;
        const u64 m2 = isOff ? mr2 : ~mr2;
        const u64 m3 = isOff ? mr3 : ~mr3;
        const unsigned p0 = __popcll(m0), p1 = __popcll(m1), p2 = __popcll(m2);
        int w; u64 m; unsigned nn;
        if (rem < p0)                { w = 0; m = m0; nn = rem; }
        else if (rem < p0 + p1)      { w = 1; m = m1; nn = rem - p0; }
        else if (rem < p0 + p1 + p2) { w = 2; m = m2; nn = rem - p0 - p1; }
        else                         { w = 3; m = m3; nn = rem - p0 - p1 - p2; }
        const int src = (int)b * 256 + w * 64 + nth_set_bit(m, nn);

        const float2 sv = stPrev[src];
        x = sv.x; isOn = sv.y;
        outRow[i] = x;
        if (mode == 2) return;
    }

    const float lin = inp[i].x;
    float x_new, isOn_new;
    bool off;
    mlp_update(lin, x, isOn, W1, b1, W2, b2, W3, b3, x_new, isOn_new, off);

    stNew[i] = make_float2(x_new, isOn_new);

    // ---- producer tail: verbatim from the verified round-7 kernel ----
    const u64 bm = __ballot(off);
    __shared__ unsigned wOff[NTHR / 64];
    if (lane == 0) { mskNew[i >> 6] = bm; wOff[wv] = (unsigned)__popcll(bm); }
    __syncthreads();
    if (tid == 0) {
        unsigned ssum = 0;
#pragma unroll
        for (int w2 = 0; w2 < NTHR / 64; ++w2) ssum += wOff[w2];
        cntNew[blockIdx.x] = ssum;
    }
}

// ---------------------------------------------------------------------------
extern "C" void kernel_launch(void* const* d_in, const int* in_sizes, int n_in,
                              void* d_out, int out_size, void* d_ws, size_t ws_size,
                              hipStream_t stream)
{
    const float2* inp = (const float2*)d_in[0];
    const float* W1 = (const float*)d_in[1];
    const float* b1 = (const float*)d_in[2];
    const float* W2 = (const float*)d_in[3];
    const float* b2 = (const float*)d_in[4];
    const float* W3 = (const float*)d_in[5];
    const float* b3 = (const float*)d_in[6];
    float* out = (float*)d_out;

    const int B = in_sizes[0] / 2;          // 262144
    const int nsteps = out_size / B;        // 40

    float2*   st0 = (float2*)d_ws;
    float2*   st1 = st0 + B;
    unsigned* cnt0 = (unsigned*)(st1 + B);
    unsigned* cnt1 = cnt0 + NCHUNK;
    u64*      msk0 = (u64*)(cnt1 + NCHUNK);
    u64*      msk1 = msk0 + (B / 64);

    // step 0: no pull
    fused_kernel<<<NBLK, NTHR, 0, stream>>>(inp, W1, b1, W2, b2, W3, b3,
                                            st0, cnt0, msk0,
                                            st0, cnt0, msk0, nullptr, 0);
    // steps 1..nsteps-1: pull prev (writes traj row t-1) + compute step t
    for (int t = 1; t < nsteps; ++t) {
        const bool odd = (t & 1);
        const float2*   stP  = odd ? st0  : st1;
        const unsigned* cntP = odd ? cnt0 : cnt1;
        const u64*      mskP = odd ? msk0 : msk1;
        float2*   stN  = odd ? st1  : st0;
        unsigned* cntN = odd ? cnt1 : cnt0;
        u64*      mskN = odd ? msk1 : msk0;
        fused_kernel<<<NBLK, NTHR, 0, stream>>>(inp, W1, b1, W2, b2, W3, b3,
                                                stP, cntP, mskP,
                                                stN, cntN, mskN,
                                                out + (size_t)(t - 1) * B, 1);
    }
    // final pull-only: traj row nsteps-1
    {
        const bool odd = (nsteps & 1);
        const float2*   stP  = odd ? st0  : st1;
        const unsigned* cntP = odd ? cnt0 : cnt1;
        const u64*      mskP = odd ? msk0 : msk1;
        fused_kernel<<<NBLK, NTHR, 0, stream>>>(inp, W1, b1, W2, b2, W3, b3,
                                                stP, cntP, mskP,
                                                st0, cnt0, msk0,
                                                out + (size_t)(nsteps - 1) * B, 2);
    }
}